// Round 12
// baseline (2661.524 us; speedup 1.0000x reference)
//
#include <hip/hip_runtime.h>
#include <cstddef>

#define NN 10000
#define NE 160000

#define S3  1.7320508075688772f
#define S5  2.2360679774997896f
#define S15 3.8729833462074170f
#define S25 0.6324555320336759f     /* sqrt(2/5) */
#define PI5 0.62831853071795864f    /* pi/5 */

/* CG path constants (analytic): CG(l,0,l)=I/sqrt(2l+1); CG(l,l,0)=(-1)^l I/sqrt(2l+1).
   Folded with the 1/AVG_NEIGH=1/16 segment-mean. */
#define C0_0 (1.f/16.f)
#define C0_1 (0.57735026918962576f/16.f)
#define C0_2 (0.44721359549995794f/16.f)
#define C1_0 (1.f/16.f)
#define C1_1 (-0.57735026918962576f/16.f)
#define C1_2 (0.44721359549995794f/16.f)

/* ---------------- workspace layout (4-byte element offsets), ~143 MB ------- */
constexpr size_t O_EACC = 0;                        // 64 f32 (zeroed)
constexpr size_t O_CNTR = 64;                       // NN int (zeroed)
constexpr size_t O_CNTS = O_CNTR + NN;
constexpr size_t O_CURR = O_CNTS + NN;
constexpr size_t O_CURS = O_CURR + NN;
constexpr size_t ZERO_ELEMS = O_CURS + NN;          // zeroed prefix
constexpr size_t O_SPEC = ZERO_ELEMS;               // NN int
constexpr size_t O_OFFR = O_SPEC + NN;              // NN+1 int
constexpr size_t O_OFFS = O_OFFR + NN + 8;          // NN+1 int
constexpr size_t O_LSTR = O_OFFS + NN + 8;          // NE int
constexpr size_t O_LSTS = O_LSTR + NE;              // NE int
constexpr size_t O_A1   = O_LSTS + NE;              // NN*64 f32
constexpr size_t O_U    = O_A1 + (size_t)NN*64;     // NE*3
constexpr size_t O_RB   = O_U + (size_t)NE*3;       // NE
constexpr size_t O_Y    = O_RB + NE;                // NE*8
constexpr size_t O_FEAT = O_Y + (size_t)NE*8;       // NE*8
constexpr size_t O_R    = O_FEAT + (size_t)NE*8;    // NE*192 bf16, R0 then R1
constexpr size_t O_AGG0 = O_R + (size_t)NE*96;      // NN*576  (agg0 then dagg0)
constexpr size_t O_H10  = O_AGG0 + (size_t)NN*576;  // NN*64
constexpr size_t O_B    = O_H10 + (size_t)NN*64;    // NN*576
constexpr size_t O_AGG1 = O_B + (size_t)NN*576;     // NN*192 (agg1 then dagg1)
constexpr size_t O_DH10 = O_AGG1 + (size_t)NN*192;  // NN*64
constexpr size_t O_WT   = O_DH10 + (size_t)NN*64;
constexpr size_t W_OUT0T = O_WT;                    // 3*4096
constexpr size_t W_UP1T  = W_OUT0T + 12288;         // 3*4096
constexpr size_t W_OUT1T = W_UP1T + 12288;          // 3*4096 (paths 0,4,9)
constexpr size_t W_SC1T  = W_OUT1T + 12288;         // 10*4096
constexpr size_t W_W2T0  = W_SC1T + 40960;          // 4096
constexpr size_t W_W3T0  = W_W2T0 + 4096;           // 4096
constexpr size_t W_W4T0  = W_W3T0 + 4096;           // 192*64   [o][k] = w4[k][o]
constexpr size_t W_W2T1  = W_W4T0 + 12288;          // 4096
constexpr size_t W_W3T1  = W_W2T1 + 4096;           // 4096
constexpr size_t W_W4T1  = W_W3T1 + 4096;           // 192*64   (cols 0,256,576 of r1w4)
constexpr size_t W_W4C1  = W_W4T1 + 12288;          // 64*192   [k][o] gathered cols of r1w4
constexpr size_t W_A1S   = W_W4C1 + 12288;          // 10*64
constexpr size_t TOTAL_ELEMS = W_A1S + 640;

__device__ __forceinline__ float rl(float v, int l){
  return __uint_as_float(__builtin_amdgcn_readlane(__float_as_uint(v), l));
}
__device__ __forceinline__ int rfl(int v){
  return __builtin_amdgcn_readfirstlane(v);
}
__device__ __forceinline__ float wred(float v){
  #pragma unroll
  for(int m=32;m;m>>=1) v += __shfl_xor(v, m, 64);
  return v;
}
__device__ __forceinline__ float silu_f(float x){ float s=1.f/(1.f+expf(-x)); return x*s; }
__device__ __forceinline__ float dsilu_f(float x){ float s=1.f/(1.f+expf(-x)); return s*(1.f+x*(1.f-s)); }
__device__ __forceinline__ unsigned short f2b(float x){
  unsigned int u=__float_as_uint(x);
  unsigned int r=(u + 0x7fffu + ((u>>16)&1u))>>16;
  return (unsigned short)r;
}
__device__ __forceinline__ float b2f(unsigned short h){
  return __uint_as_float(((unsigned int)h)<<16);
}

/* -------------------- prep: transposed weights + per-species A1 ----------- */
__global__ __launch_bounds__(256) void k_prep(
    const float* __restrict__ w_out0, const float* __restrict__ w_up1,
    const float* __restrict__ w_out1, const float* __restrict__ w_sc1,
    const float* __restrict__ r0w2, const float* __restrict__ r0w3, const float* __restrict__ r0w4,
    const float* __restrict__ r1w2, const float* __restrict__ r1w3, const float* __restrict__ r1w4,
    const float* __restrict__ w_emb, const float* __restrict__ w_up0,
    float* __restrict__ ws)
{
  int t = blockIdx.x*256 + threadIdx.x;
  if (t < 12288){
    int l=t>>12, rem=t&4095, a=rem>>6, b=rem&63;
    ws[W_OUT0T+t] = w_out0[l*4096 + b*64 + a];
    ws[W_UP1T +t] = w_up1 [l*4096 + b*64 + a];
    int pl = (l==0)?0:((l==1)?4:9);
    ws[W_OUT1T+t] = w_out1[pl*4096 + b*64 + a];
  }
  if (t < 40960){
    int s=t>>12, rem=t&4095, a=rem>>6, b=rem&63;
    ws[W_SC1T+t] = w_sc1[(size_t)s*4096 + b*64 + a];
  }
  if (t < 4096){
    int a=t>>6, b=t&63;
    ws[W_W2T0+t]=r0w2[b*64+a];
    ws[W_W3T0+t]=r0w3[b*64+a];
    ws[W_W2T1+t]=r1w2[b*64+a];
    ws[W_W3T1+t]=r1w3[b*64+a];
  }
  if (t < 12288){
    int o=t>>6, k=t&63;
    ws[W_W4T0+t]=r0w4[k*192+o];
    int p=o>>6, c=o&63;
    int base=(p==0)?0:((p==1)?256:576);
    ws[W_W4T1+t]=r1w4[k*832+base+c];
  }
  if (t < 12288){
    int k=t/192, o=t%192;
    int p=o>>6, c=o&63;
    int base=(p==0)?0:((p==1)?256:576);
    ws[W_W4C1+t]=r1w4[k*832+base+c];
  }
  if (t < 640){
    int sp=t>>6, c=t&63;
    float acc=0.f;
    for(int k=0;k<64;k++) acc += w_emb[sp*64+k]*w_up0[k*64+c];
    ws[W_A1S+t]=acc;
  }
}

/* -------------------- species / embedding / e0 ---------------------------- */
__global__ __launch_bounds__(256) void k_spec(
    const float* __restrict__ attrs, const float* __restrict__ A1spec,
    const float* __restrict__ aen, const int* __restrict__ batch,
    int* __restrict__ spec, float* __restrict__ A1, float* __restrict__ eacc)
{
  int wv=(blockIdx.x*blockDim.x+threadIdx.x)>>6;
  if (wv>=NN) return;
  int lane=threadIdx.x&63;
  int sp=0;
  #pragma unroll
  for(int t=0;t<10;t++) if (attrs[(size_t)wv*10+t]>0.5f) sp=t;
  A1[(size_t)wv*64+lane]=A1spec[sp*64+lane];
  if(lane==0){
    spec[wv]=sp;
    atomicAdd(&eacc[batch[wv]*3+0], aen[sp]);
  }
}

/* ------ edge geometry: u, r, Y(l<=2), radial feats, + degree counts ------- */
__global__ __launch_bounds__(256) void k_geom(
    const float* __restrict__ pos, const float* __restrict__ shifts, const int* __restrict__ ei,
    float* __restrict__ ub, float* __restrict__ rb, float* __restrict__ Yb, float* __restrict__ fb,
    int* __restrict__ cntr, int* __restrict__ cnts)
{
  int e=blockIdx.x*256+threadIdx.x;
  if(e>=NE) return;
  int s=ei[e], rv=ei[NE+e];
  atomicAdd(&cnts[s],1);
  atomicAdd(&cntr[rv],1);
  float vx=pos[rv*3+0]-pos[s*3+0]+shifts[(size_t)e*3+0];
  float vy=pos[rv*3+1]-pos[s*3+1]+shifts[(size_t)e*3+1];
  float vz=pos[rv*3+2]-pos[s*3+2]+shifts[(size_t)e*3+2];
  float r=sqrtf(vx*vx+vy*vy+vz*vz+1e-12f);
  float inv=1.f/r;
  float x=vx*inv, y=vy*inv, z=vz*inv;
  ub[(size_t)e*3+0]=x; ub[(size_t)e*3+1]=y; ub[(size_t)e*3+2]=z;
  rb[e]=r;
  size_t yo=(size_t)e*8;
  Yb[yo+0]=S3*y;     Yb[yo+1]=S3*z;     Yb[yo+2]=S3*x;
  Yb[yo+3]=S15*x*y;  Yb[yo+4]=S15*y*z;  Yb[yo+5]=0.5f*S5*(3.f*z*z-1.f);
  Yb[yo+6]=S15*x*z;  Yb[yo+7]=0.5f*S15*(x*x-y*y);
  float u5=r*0.2f, fc=0.f;
  if(u5<1.f){
    float u2=u5*u5,u4=u2*u2,p5=u4*u5,p6=p5*u5,p7=p6*u5;
    fc=1.f-21.f*p5+35.f*p6-15.f*p7;
  }
  size_t fo=(size_t)e*8;
  #pragma unroll
  for(int n=1;n<=8;n++) fb[fo+n-1]=S25*sinf(n*PI5*r)*inv*fc;
}

/* -------------------- CSR: both scans in one launch (2 blocks) ------------- */
__global__ __launch_bounds__(1024) void k_scan2(
    const int* __restrict__ cntr, const int* __restrict__ cnts,
    int* __restrict__ offr, int* __restrict__ offs)
{
  const int* __restrict__ cnt = blockIdx.x ? cnts : cntr;
  int* __restrict__ off = blockIdx.x ? offs : offr;
  __shared__ int sh[1024];
  __shared__ int sbase;
  int tid=threadIdx.x;
  if(tid==0) sbase=0;
  __syncthreads();
  for(int start=0;start<NN;start+=1024){
    int i=start+tid;
    int v=(i<NN)?cnt[i]:0;
    sh[tid]=v;
    __syncthreads();
    for(int o=1;o<1024;o<<=1){
      int t=(tid>=o)?sh[tid-o]:0;
      __syncthreads();
      sh[tid]+=t;
      __syncthreads();
    }
    int excl=sbase+sh[tid]-v;
    int tot=sh[1023];
    __syncthreads();
    if(i<NN) off[i]=excl;
    if(tid==0) sbase+=tot;
    __syncthreads();
  }
  if(tid==0) off[NN]=sbase;
}

__global__ __launch_bounds__(256) void k_fill(const int* __restrict__ ei,
    const int* __restrict__ offr, const int* __restrict__ offs,
    int* __restrict__ curr, int* __restrict__ curs,
    int* __restrict__ lstr, int* __restrict__ lsts)
{
  int e=blockIdx.x*256+threadIdx.x;
  if(e>=NE) return;
  int s=ei[e], rv=ei[NE+e];
  int p=atomicAdd(&curr[rv],1); lstr[offr[rv]+p]=e;
  int q=atomicAdd(&curs[s],1);  lsts[offs[s]+q]=e;
}

/* -------------------- radial MLP forward (wave = 2 edges), bf16 out -------- */
__global__ __launch_bounds__(256) void k_mlp(
    const float* __restrict__ feat,
    const float* __restrict__ w1, const float* __restrict__ w2,
    const float* __restrict__ w3, const float* __restrict__ w4c,
    unsigned short* __restrict__ R)
{
  __shared__ float lw4[12288];
  for(int i=threadIdx.x;i<12288;i+=256) lw4[i]=w4c[i];
  __syncthreads();
  int lane=threadIdx.x&63;
  int wv=(blockIdx.x*blockDim.x+threadIdx.x)>>6;
  int nwv=(gridDim.x*blockDim.x)>>6;
  for(int pr=wv; pr<NE/2; pr+=nwv){
    size_t e0=(size_t)pr*2, e1=e0+1;
    float za=0.f, zb=0.f;
    #pragma unroll
    for(int b=0;b<8;b++){
      float w=w1[b*64+lane];
      za+=feat[e0*8+b]*w; zb+=feat[e1*8+b]*w;
    }
    float ta=silu_f(za), tb=silu_f(zb);
    za=0.f; zb=0.f;
    #pragma unroll 8
    for(int k=0;k<64;k++){ float w=w2[k*64+lane]; za+=rl(ta,k)*w; zb+=rl(tb,k)*w; }
    ta=silu_f(za); tb=silu_f(zb);
    za=0.f; zb=0.f;
    #pragma unroll 8
    for(int k=0;k<64;k++){ float w=w3[k*64+lane]; za+=rl(ta,k)*w; zb+=rl(tb,k)*w; }
    ta=silu_f(za); tb=silu_f(zb);
    float oa0=0,oa1=0,oa2=0,ob0=0,ob1=0,ob2=0;
    #pragma unroll 4
    for(int k=0;k<64;k++){
      float va=rl(ta,k), vb=rl(tb,k);
      float wA=lw4[k*192+lane], wB=lw4[k*192+64+lane], wC=lw4[k*192+128+lane];
      oa0+=va*wA; oa1+=va*wB; oa2+=va*wC;
      ob0+=vb*wA; ob1+=vb*wB; ob2+=vb*wC;
    }
    R[e0*192+lane]=f2b(oa0); R[e0*192+64+lane]=f2b(oa1); R[e0*192+128+lane]=f2b(oa2);
    R[e1*192+lane]=f2b(ob0); R[e1*192+64+lane]=f2b(ob1); R[e1*192+128+lane]=f2b(ob2);
  }
}

/* -------------------- interaction 1 aggregation (gather by receiver) ------- */
__global__ __launch_bounds__(256) void k_agg0(
    const int* __restrict__ ei, const int* __restrict__ offr, const int* __restrict__ lstr,
    const float* __restrict__ A1, const unsigned short* __restrict__ R0, const float* __restrict__ Yb,
    float* __restrict__ agg0)
{
  int wv=(blockIdx.x*blockDim.x+threadIdx.x)>>6;
  if(wv>=NN) return;
  int lane=threadIdx.x&63;
  float a[9];
  #pragma unroll
  for(int q=0;q<9;q++) a[q]=0.f;
  int i0=rfl(offr[wv]), i1=rfl(offr[wv+1]);
  for(int i=i0;i<i1;i++){
    int e=rfl(lstr[i]);
    int s=rfl(ei[e]);
    const float* a1p=&A1[(size_t)s*64];
    const unsigned short* rp=&R0[(size_t)e*192];
    const float* Yv=&Yb[(size_t)e*8];
    float a1=a1p[lane];
    float t0=a1*b2f(rp[lane]);
    float t1=a1*b2f(rp[64+lane]);
    float t2=a1*b2f(rp[128+lane]);
    a[0]+=t0;
    #pragma unroll
    for(int j=0;j<3;j++) a[1+j]+=Yv[j]*t1;
    #pragma unroll
    for(int j=0;j<5;j++) a[4+j]+=Yv[3+j]*t2;
  }
  size_t o=(size_t)wv*576;
  agg0[o+lane]=a[0]*C0_0;
  #pragma unroll
  for(int j=0;j<3;j++) agg0[o+(1+j)*64+lane]=a[1+j]*C0_1;
  #pragma unroll
  for(int j=0;j<5;j++) agg0[o+(4+j)*64+lane]=a[4+j]*C0_2;
}

/* -------------------- h1 (+sc, e1) and B = h1 @ w_up1 ---------------------- */
__global__ __launch_bounds__(256) void k_h1B(
    const float* __restrict__ agg0, const float* __restrict__ w_out0,
    const float* __restrict__ w_emb, const float* __restrict__ w_sc0,
    const float* __restrict__ w_up1, const float* __restrict__ w_r0,
    const int* __restrict__ spec, const int* __restrict__ batch,
    float* __restrict__ h1_0, float* __restrict__ Bv, float* __restrict__ eacc)
{
  int wv=(blockIdx.x*blockDim.x+threadIdx.x)>>6;
  if(wv>=NN) return;
  int lane=threadIdx.x&63;
  float aq[9], h[9];
  #pragma unroll
  for(int q=0;q<9;q++){ aq[q]=agg0[(size_t)wv*576+q*64+lane]; h[q]=0.f; }
  #pragma unroll 4
  for(int c=0;c<64;c++){
    float w0=w_out0[c*64+lane], wl1=w_out0[4096+c*64+lane], wl2=w_out0[8192+c*64+lane];
    h[0]+=rl(aq[0],c)*w0;
    h[1]+=rl(aq[1],c)*wl1; h[2]+=rl(aq[2],c)*wl1; h[3]+=rl(aq[3],c)*wl1;
    h[4]+=rl(aq[4],c)*wl2; h[5]+=rl(aq[5],c)*wl2; h[6]+=rl(aq[6],c)*wl2;
    h[7]+=rl(aq[7],c)*wl2; h[8]+=rl(aq[8],c)*wl2;
  }
  int sp=rfl(spec[wv]);
  #pragma unroll 8
  for(int c=0;c<64;c++) h[0]+=w_emb[sp*64+c]*w_sc0[(size_t)sp*4096+c*64+lane];
  h1_0[(size_t)wv*64+lane]=h[0];
  float p=wred(h[0]*w_r0[lane]);
  if(lane==0) atomicAdd(&eacc[batch[wv]*3+1],p);
  float Bo[9];
  #pragma unroll
  for(int q=0;q<9;q++) Bo[q]=0.f;
  #pragma unroll 4
  for(int c=0;c<64;c++){
    float u0=w_up1[c*64+lane], u1=w_up1[4096+c*64+lane], u2=w_up1[8192+c*64+lane];
    Bo[0]+=rl(h[0],c)*u0;
    Bo[1]+=rl(h[1],c)*u1; Bo[2]+=rl(h[2],c)*u1; Bo[3]+=rl(h[3],c)*u1;
    Bo[4]+=rl(h[4],c)*u2; Bo[5]+=rl(h[5],c)*u2; Bo[6]+=rl(h[6],c)*u2;
    Bo[7]+=rl(h[7],c)*u2; Bo[8]+=rl(h[8],c)*u2;
  }
  #pragma unroll
  for(int q=0;q<9;q++) Bv[(size_t)wv*576+q*64+lane]=Bo[q];
}

/* -------------------- interaction 2 aggregation (l3=0 paths) --------------- */
__global__ __launch_bounds__(256) void k_agg1(
    const int* __restrict__ ei, const int* __restrict__ offr, const int* __restrict__ lstr,
    const float* __restrict__ Bv, const unsigned short* __restrict__ R1, const float* __restrict__ Yb,
    float* __restrict__ agg1)
{
  int wv=(blockIdx.x*blockDim.x+threadIdx.x)>>6;
  if(wv>=NN) return;
  int lane=threadIdx.x&63;
  float accA=0.f, accB=0.f, accC=0.f;
  int i0=rfl(offr[wv]), i1=rfl(offr[wv+1]);
  for(int i=i0;i<i1;i++){
    int e=rfl(lstr[i]);
    int s=rfl(ei[e]);
    const float* Bq=&Bv[(size_t)s*576];
    const unsigned short* rp=&R1[(size_t)e*192];
    const float* Yv=&Yb[(size_t)e*8];
    accA += b2f(rp[lane])*Bq[lane];
    float tb=0.f;
    #pragma unroll
    for(int j=0;j<3;j++) tb += Yv[j]*Bq[(1+j)*64+lane];
    accB += b2f(rp[64+lane])*tb;
    float tc=0.f;
    #pragma unroll
    for(int j=0;j<5;j++) tc += Yv[3+j]*Bq[(4+j)*64+lane];
    accC += b2f(rp[128+lane])*tc;
  }
  agg1[(size_t)wv*192+lane]     = accA*C1_0;
  agg1[(size_t)wv*192+64+lane]  = accB*C1_1;
  agg1[(size_t)wv*192+128+lane] = accC*C1_2;
}

/* ------- h2, e2, g2; dagg1 written IN PLACE over agg1 (same wave slots) ---- */
__global__ __launch_bounds__(256) void k_h2g2(
    float* __restrict__ agg1, const float* __restrict__ h1_0,
    const float* __restrict__ w_out1, const float* __restrict__ w_sc1,
    const float* __restrict__ w_m1, const float* __restrict__ w_m2,
    const float* __restrict__ w_r0,
    const float* __restrict__ w_out1T, const float* __restrict__ w_sc1T,
    const int* __restrict__ spec, const int* __restrict__ batch,
    float* __restrict__ dh10, float* __restrict__ eacc)
{
  int wv=(blockIdx.x*blockDim.x+threadIdx.x)>>6;
  if(wv>=NN) return;
  int lane=threadIdx.x&63;
  int sp=rfl(spec[wv]);
  float a0=agg1[(size_t)wv*192+lane], a1=agg1[(size_t)wv*192+64+lane], a2=agg1[(size_t)wv*192+128+lane];
  float hh=h1_0[(size_t)wv*64+lane];
  float h2=0.f;
  #pragma unroll 4
  for(int c=0;c<64;c++){
    h2 += rl(a0,c)*w_out1[c*64+lane];
    h2 += rl(a1,c)*w_out1[4*4096+c*64+lane];
    h2 += rl(a2,c)*w_out1[9*4096+c*64+lane];
    h2 += rl(hh,c)*w_sc1[(size_t)sp*4096+c*64+lane];
  }
  int tt=lane&15;
  float z=0.f;
  #pragma unroll 8
  for(int d=0;d<64;d++) z+=rl(h2,d)*w_m1[d*16+tt];
  float sg=1.f/(1.f+expf(-z));
  float e2p=(lane<16)? w_m2[tt]*z*sg : 0.f;
  e2p=wred(e2p);
  if(lane==0) atomicAdd(&eacc[batch[wv]*3+2],e2p);
  float st=w_m2[tt]*sg*(1.f+z*(1.f-sg));
  float g=0.f;
  #pragma unroll
  for(int t=0;t<16;t++) g+=rl(st,t)*w_m1[lane*16+t];
  float d0=0.f,d1=0.f,d2=0.f,dh=0.f;
  #pragma unroll 4
  for(int d=0;d<64;d++){
    float gd=rl(g,d);
    d0+=gd*w_out1T[d*64+lane];
    d1+=gd*w_out1T[4096+d*64+lane];
    d2+=gd*w_out1T[8192+d*64+lane];
    dh+=gd*w_sc1T[(size_t)sp*4096+d*64+lane];
  }
  agg1[(size_t)wv*192+lane]=d0;
  agg1[(size_t)wv*192+64+lane]=d1;
  agg1[(size_t)wv*192+128+lane]=d2;
  dh10[(size_t)wv*64+lane]=dh+w_r0[lane];
}

/* --- dB (gather by sender) -> dh1 -> dagg0 (written over agg0 buffer) ------ */
__global__ __launch_bounds__(256) void k_dB(
    const int* __restrict__ ei, const int* __restrict__ offs, const int* __restrict__ lsts,
    const float* __restrict__ dagg1, const unsigned short* __restrict__ R1, const float* __restrict__ Yb,
    const float* __restrict__ w_up1T, const float* __restrict__ w_out0T,
    const float* __restrict__ dh10,
    float* __restrict__ dagg0)
{
  int wv=(blockIdx.x*blockDim.x+threadIdx.x)>>6;
  if(wv>=NN) return;
  int lane=threadIdx.x&63;
  float dB[9];
  #pragma unroll
  for(int q=0;q<9;q++) dB[q]=0.f;
  int i0=rfl(offs[wv]), i1=rfl(offs[wv+1]);
  for(int i=i0;i<i1;i++){
    int e=rfl(lsts[i]);
    int rv=rfl(ei[NE+e]);
    const float* dq=&dagg1[(size_t)rv*192];
    const unsigned short* rp=&R1[(size_t)e*192];
    const float* Yv=&Yb[(size_t)e*8];
    float t0=dq[lane]*C1_0*b2f(rp[lane]);
    float t1=dq[64+lane]*C1_1*b2f(rp[64+lane]);
    float t2=dq[128+lane]*C1_2*b2f(rp[128+lane]);
    dB[0]+=t0;
    #pragma unroll
    for(int j=0;j<3;j++) dB[1+j]+=t1*Yv[j];
    #pragma unroll
    for(int j=0;j<5;j++) dB[4+j]+=t2*Yv[3+j];
  }
  float dh[9];
  #pragma unroll
  for(int q=0;q<9;q++) dh[q]=0.f;
  #pragma unroll 4
  for(int c=0;c<64;c++){
    float u0=w_up1T[c*64+lane], u1=w_up1T[4096+c*64+lane], u2=w_up1T[8192+c*64+lane];
    dh[0]+=rl(dB[0],c)*u0;
    dh[1]+=rl(dB[1],c)*u1; dh[2]+=rl(dB[2],c)*u1; dh[3]+=rl(dB[3],c)*u1;
    dh[4]+=rl(dB[4],c)*u2; dh[5]+=rl(dB[5],c)*u2; dh[6]+=rl(dB[6],c)*u2;
    dh[7]+=rl(dB[7],c)*u2; dh[8]+=rl(dB[8],c)*u2;
  }
  dh[0]+=dh10[(size_t)wv*64+lane];
  float dg[9];
  #pragma unroll
  for(int q=0;q<9;q++) dg[q]=0.f;
  #pragma unroll 4
  for(int d=0;d<64;d++){
    float o0=w_out0T[d*64+lane], o1=w_out0T[4096+d*64+lane], o2=w_out0T[8192+d*64+lane];
    dg[0]+=rl(dh[0],d)*o0;
    dg[1]+=rl(dh[1],d)*o1; dg[2]+=rl(dh[2],d)*o1; dg[3]+=rl(dh[3],d)*o1;
    dg[4]+=rl(dh[4],d)*o2; dg[5]+=rl(dh[5],d)*o2; dg[6]+=rl(dh[6],d)*o2;
    dg[7]+=rl(dh[7],d)*o2; dg[8]+=rl(dh[8],d)*o2;
  }
  #pragma unroll
  for(int q=0;q<9;q++) dagg0[(size_t)wv*576+q*64+lane]=dg[q];
}

/* ---- MLP forward (4 edges/wave, lane=channel); RC: also R cols 1,2 ------- */
template<bool RC>
__device__ __forceinline__ void mlp_fwd4(
    int lane, int eb0, const float* __restrict__ feat,
    const float* __restrict__ w1, const float* __restrict__ w2,
    const float* __restrict__ w3, const float* __restrict__ w4C,
    float z1[4], float z2[4], float z3[4], float rc0[4], float rc1[4])
{
  float t[4], acc[4];
  #pragma unroll
  for(int i=0;i<4;i++) z1[i]=0.f;
  #pragma unroll
  for(int b=0;b<8;b++){
    float w=w1[b*64+lane];
    #pragma unroll
    for(int i=0;i<4;i++) z1[i]+=feat[(size_t)(eb0+i)*8+b]*w;
  }
  #pragma unroll
  for(int i=0;i<4;i++){ t[i]=silu_f(z1[i]); acc[i]=0.f; }
  #pragma unroll 8
  for(int k=0;k<64;k++){
    float w=w2[k*64+lane];
    #pragma unroll
    for(int i=0;i<4;i++) acc[i]+=rl(t[i],k)*w;
  }
  #pragma unroll
  for(int i=0;i<4;i++){ z2[i]=acc[i]; t[i]=silu_f(acc[i]); acc[i]=0.f; }
  #pragma unroll 8
  for(int k=0;k<64;k++){
    float w=w3[k*64+lane];
    #pragma unroll
    for(int i=0;i<4;i++) acc[i]+=rl(t[i],k)*w;
  }
  #pragma unroll
  for(int i=0;i<4;i++) z3[i]=acc[i];
  if(RC){
    float a2[4];
    #pragma unroll
    for(int i=0;i<4;i++){ t[i]=silu_f(z3[i]); acc[i]=0.f; a2[i]=0.f; }
    #pragma unroll 8
    for(int k=0;k<64;k++){
      float wB=w4C[k*192+64+lane], wC=w4C[k*192+128+lane];
      #pragma unroll
      for(int i=0;i<4;i++){ float v=rl(t[i],k); acc[i]+=v*wB; a2[i]+=v*wC; }
    }
    #pragma unroll
    for(int i=0;i<4;i++){ rc0[i]=acc[i]; rc1[i]=a2[i]; }
  }
}

/* ---- MLP backward core (4 edges): dR -> dracc += dz1*q (per-lane) --------- */
__device__ __forceinline__ void mlp_bwd4(
    int lane,
    const float* __restrict__ w2T, const float* __restrict__ w3T,
    const float* __restrict__ w4T,
    const float z1[4], const float z2[4], const float z3[4],
    const float dRa[4], const float dRb[4], const float dRc[4],
    const float qv[4], float dracc[4])
{
  float t[4], acc[4];
  #pragma unroll
  for(int i=0;i<4;i++) acc[i]=0.f;
  #pragma unroll 8
  for(int k=0;k<64;k++){
    float w=w4T[k*64+lane];
    #pragma unroll
    for(int i=0;i<4;i++) acc[i]+=rl(dRa[i],k)*w;
  }
  #pragma unroll 8
  for(int k=0;k<64;k++){
    float w=w4T[4096+k*64+lane];
    #pragma unroll
    for(int i=0;i<4;i++) acc[i]+=rl(dRb[i],k)*w;
  }
  #pragma unroll 8
  for(int k=0;k<64;k++){
    float w=w4T[8192+k*64+lane];
    #pragma unroll
    for(int i=0;i<4;i++) acc[i]+=rl(dRc[i],k)*w;
  }
  #pragma unroll
  for(int i=0;i<4;i++){ t[i]=acc[i]*dsilu_f(z3[i]); acc[i]=0.f; }
  #pragma unroll 8
  for(int k=0;k<64;k++){
    float w=w3T[k*64+lane];
    #pragma unroll
    for(int i=0;i<4;i++) acc[i]+=rl(t[i],k)*w;
  }
  #pragma unroll
  for(int i=0;i<4;i++){ t[i]=acc[i]*dsilu_f(z2[i]); acc[i]=0.f; }
  #pragma unroll 8
  for(int k=0;k<64;k++){
    float w=w2T[k*64+lane];
    #pragma unroll
    for(int i=0;i<4;i++) acc[i]+=rl(t[i],k)*w;
  }
  #pragma unroll
  for(int i=0;i<4;i++) dracc[i]+=acc[i]*dsilu_f(z1[i])*qv[i];
}

/* ------ merged edge backward: both MLPs, 4 wreds/edge total ----------------
   Wave-uniform gather bases hoisted to SGPR via readfirstlane (rfl). */
__global__ __launch_bounds__(256) void k_ebwd(
    const int* __restrict__ ei,
    const float* __restrict__ A1, const float* __restrict__ Bv,
    const float* __restrict__ dagg0, const float* __restrict__ dagg1,
    const float* __restrict__ Yb, const float* __restrict__ feat,
    const unsigned short* __restrict__ Rh,
    const float* __restrict__ ub, const float* __restrict__ rb,
    const float* __restrict__ w1_0, const float* __restrict__ w2_0, const float* __restrict__ w3_0,
    const float* __restrict__ w2T0, const float* __restrict__ w3T0, const float* __restrict__ w4T0,
    const float* __restrict__ w4C0,
    const float* __restrict__ w1_1, const float* __restrict__ w2_1, const float* __restrict__ w3_1,
    const float* __restrict__ w2T1, const float* __restrict__ w3T1, const float* __restrict__ w4T1,
    float* __restrict__ F)
{
  int wv=(blockIdx.x*blockDim.x+threadIdx.x)>>6;
  int lane=threadIdx.x&63;
  int eb0=rfl(wv*4);
  if(eb0>=NE) return;

  /* shared radial-derivative prelude: lane (i*8+b) handles edge i, bessel b */
  int i8=(lane>>3)&3, b8=lane&7;
  float re=rb[eb0+i8];
  float ivre=1.f/re;
  float u5=re*0.2f, fcut=0.f, dfcut=0.f;
  if(u5<1.f){
    float u2=u5*u5,u4=u2*u2,p5=u4*u5,p6=p5*u5,p7=p6*u5;
    fcut=1.f-21.f*p5+35.f*p6-15.f*p7;
    dfcut=(-105.f*u4+210.f*p5-105.f*p6)*0.2f;
  }
  float kn=(b8+1)*PI5;
  float sn,cn; sincosf(kn*re,&sn,&cn);
  float radv=(S25*(kn*cn-sn*ivre)*ivre)*fcut + (S25*sn*ivre)*dfcut;

  float q0[4], q1[4], dracc[4], gxl[4], gyl[4], gzl[4];
  #pragma unroll
  for(int i=0;i<4;i++){ q0[i]=0.f; q1[i]=0.f; dracc[i]=0.f; }
  #pragma unroll
  for(int b=0;b<8;b++){
    float wa=w1_0[b*64+lane], wb=w1_1[b*64+lane];
    #pragma unroll
    for(int i=0;i<4;i++){
      float rv_=rl(radv,i*8+b);
      q0[i]+=rv_*wa; q1[i]+=rv_*wb;
    }
  }

  /* ---------------- Phase A: MLP0 + dagg0 side ---------------- */
  float z1[4],z2[4],z3[4],rc0[4],rc1[4];
  mlp_fwd4<true>(lane, eb0, feat, w1_0, w2_0, w3_0, w4C0, z1,z2,z3, rc0,rc1);

  float dRa[4],dRb[4],dRc[4];
  #pragma unroll
  for(int i=0;i<4;i++){
    int e=eb0+i;
    int s=rfl(ei[e]), rv=rfl(ei[NE+e]);
    const float* a1p=&A1[(size_t)s*64];
    const float* dg=&dagg0[(size_t)rv*576];
    const float* Yv=&Yb[(size_t)e*8];
    float A1a=a1p[lane];
    float P0=C0_1*A1a*rc0[i], P1=C0_2*A1a*rc1[i];
    dRa[i]=C0_0*A1a*dg[lane];
    float ux=ub[(size_t)e*3], uy=ub[(size_t)e*3+1], uz=ub[(size_t)e*3+2];
    float d0=dg[64+lane],  d1=dg[128+lane], d2=dg[192+lane];
    float d3=dg[256+lane], d4=dg[320+lane], d5=dg[384+lane];
    float d6=dg[448+lane], d7=dg[512+lane];
    float s1=Yv[0]*d0+Yv[1]*d1+Yv[2]*d2;
    float s2=Yv[3]*d3+Yv[4]*d4+Yv[5]*d5+Yv[6]*d6+Yv[7]*d7;
    float y0=P0*d0, y1=P0*d1, y2=P0*d2;
    float y3=P1*d3, y4=P1*d4, y5=P1*d5, y6=P1*d6, y7=P1*d7;
    gxl[i]=S3*y2+S15*(y3*uy+y6*uz)+S15*y7*ux;
    gyl[i]=S3*y0+S15*(y3*ux+y4*uz)-S15*y7*uy;
    gzl[i]=S3*y1+S15*(y4*uy+y6*ux)+3.f*S5*y5*uz;
    dRb[i]=C0_1*A1a*s1;
    dRc[i]=C0_2*A1a*s2;
  }
  mlp_bwd4(lane, w2T0, w3T0, w4T0, z1,z2,z3, dRa,dRb,dRc, q0, dracc);

  /* ---------------- Phase B: MLP1 + Bv/dagg1 side ---------------- */
  mlp_fwd4<false>(lane, eb0, feat, w1_1, w2_1, w3_1, nullptr, z1,z2,z3, rc0,rc1);

  #pragma unroll
  for(int i=0;i<4;i++){
    int e=eb0+i;
    int s=rfl(ei[e]), rv=rfl(ei[NE+e]);
    const float* Bq=&Bv[(size_t)s*576];
    const float* dq=&dagg1[(size_t)rv*192];
    const float* Yv=&Yb[(size_t)e*8];
    const unsigned short* rp=&Rh[(size_t)e*192];
    float dq0=dq[lane], dq1=dq[64+lane], dq2=dq[128+lane];
    float r1c0=b2f(rp[64+lane]);
    float r1c1=b2f(rp[128+lane]);
    float P1=C1_1*r1c0*dq1, P2=C1_2*r1c1*dq2;
    dRa[i]=C1_0*dq0*Bq[lane];
    float b0=Bq[64+lane],  b1=Bq[128+lane], b2=Bq[192+lane];
    float b3=Bq[256+lane], b4=Bq[320+lane], b5=Bq[384+lane];
    float b6=Bq[448+lane], b7=Bq[512+lane];
    float s1=Yv[0]*b0+Yv[1]*b1+Yv[2]*b2;
    float s2=Yv[3]*b3+Yv[4]*b4+Yv[5]*b5+Yv[6]*b6+Yv[7]*b7;
    float y0=P1*b0, y1=P1*b1, y2=P1*b2;
    float y3=P2*b3, y4=P2*b4, y5=P2*b5, y6=P2*b6, y7=P2*b7;
    float ux=ub[(size_t)e*3], uy=ub[(size_t)e*3+1], uz=ub[(size_t)e*3+2];
    gxl[i]+=S3*y2+S15*(y3*uy+y6*uz)+S15*y7*ux;
    gyl[i]+=S3*y0+S15*(y3*ux+y4*uz)-S15*y7*uy;
    gzl[i]+=S3*y1+S15*(y4*uy+y6*ux)+3.f*S5*y5*uz;
    dRb[i]=C1_1*dq1*s1;
    dRc[i]=C1_2*dq2*s2;
  }
  mlp_bwd4(lane, w2T1, w3T1, w4T1, z1,z2,z3, dRa,dRb,dRc, q1, dracc);

  /* ---------------- finalize: 4 wreds per edge, forces ---------------- */
  #pragma unroll
  for(int i=0;i<4;i++){
    int e=eb0+i;
    int s=rfl(ei[e]), rv=rfl(ei[NE+e]);
    float gx=wred(gxl[i]);
    float gy=wred(gyl[i]);
    float gz=wred(gzl[i]);
    float dr=wred(dracc[i]);
    float ivr=1.f/rb[e];
    float ux=ub[(size_t)e*3], uy=ub[(size_t)e*3+1], uz=ub[(size_t)e*3+2];
    float dot=gx*ux+gy*uy+gz*uz;
    float dvx=(gx-dot*ux)*ivr+dr*ux;
    float dvy=(gy-dot*uy)*ivr+dr*uy;
    float dvz=(gz-dot*uz)*ivr+dr*uz;
    if(lane==0){
      atomicAdd(&F[rv*3+0],-dvx); atomicAdd(&F[rv*3+1],-dvy); atomicAdd(&F[rv*3+2],-dvz);
      atomicAdd(&F[s*3+0],  dvx); atomicAdd(&F[s*3+1],  dvy); atomicAdd(&F[s*3+2],  dvz);
    }
  }
}

/* -------------------- finalize energies ------------------------------------ */
__global__ __launch_bounds__(64) void k_final(const float* __restrict__ eacc, float* __restrict__ out)
{
  int g=threadIdx.x;
  if(g<16){
    float a=eacc[g*3], b=eacc[g*3+1], c=eacc[g*3+2];
    out[g]=a+b+c;
    out[16+g*3+0]=a; out[16+g*3+1]=b; out[16+g*3+2]=c;
  }
}

extern "C" void kernel_launch(void* const* d_in, const int* in_sizes, int n_in,
                              void* d_out, int out_size, void* d_ws, size_t ws_size,
                              hipStream_t stream)
{
  (void)in_sizes; (void)n_in;
  if (ws_size < TOTAL_ELEMS*sizeof(float)) return;

  const float* pos   =(const float*)d_in[0];
  const float* attrs =(const float*)d_in[1];
  const float* shifts=(const float*)d_in[2];
  const float* aen   =(const float*)d_in[3];
  const float* w_emb =(const float*)d_in[4];
  const float* w_up0 =(const float*)d_in[5];
  const float* r0w1  =(const float*)d_in[6];
  const float* r0w2  =(const float*)d_in[7];
  const float* r0w3  =(const float*)d_in[8];
  const float* r0w4  =(const float*)d_in[9];
  const float* w_out0=(const float*)d_in[10];
  const float* w_sc0 =(const float*)d_in[11];
  const float* w_r0  =(const float*)d_in[12];
  const float* w_up1 =(const float*)d_in[13];
  const float* r1w1  =(const float*)d_in[14];
  const float* r1w2  =(const float*)d_in[15];
  const float* r1w3  =(const float*)d_in[16];
  const float* r1w4  =(const float*)d_in[17];
  const float* w_out1=(const float*)d_in[18];
  const float* w_sc1 =(const float*)d_in[19];
  const float* w_m1  =(const float*)d_in[20];
  const float* w_m2  =(const float*)d_in[21];
  const int*   ei    =(const int*)d_in[22];
  const int*   batch =(const int*)d_in[23];

  float* wsf=(float*)d_ws;
  int*   wsi=(int*)d_ws;
  unsigned short* Rh=(unsigned short*)(wsf+O_R);
  float* out=(float*)d_out;

  hipMemsetAsync(d_ws, 0, ZERO_ELEMS*sizeof(float), stream);
  hipMemsetAsync(d_out, 0, (size_t)out_size*sizeof(float), stream);

  k_prep<<<160,256,0,stream>>>(w_out0,w_up1,w_out1,w_sc1,r0w2,r0w3,r0w4,r1w2,r1w3,r1w4,w_emb,w_up0,wsf);
  k_spec<<<NN/4,256,0,stream>>>(attrs, wsf+W_A1S, aen, batch, wsi+O_SPEC, wsf+O_A1, wsf+O_EACC);
  k_geom<<<(NE+255)/256,256,0,stream>>>(pos, shifts, ei, wsf+O_U, wsf+O_RB, wsf+O_Y, wsf+O_FEAT,
                                        wsi+O_CNTR, wsi+O_CNTS);
  k_scan2<<<2,1024,0,stream>>>(wsi+O_CNTR, wsi+O_CNTS, wsi+O_OFFR, wsi+O_OFFS);
  k_fill<<<(NE+255)/256,256,0,stream>>>(ei, wsi+O_OFFR, wsi+O_OFFS, wsi+O_CURR, wsi+O_CURS, wsi+O_LSTR, wsi+O_LSTS);
  /* R buffer holds R0 here */
  k_mlp<<<1024,256,0,stream>>>(wsf+O_FEAT, r0w1, r0w2, r0w3, r0w4, Rh);
  k_agg0<<<NN/4,256,0,stream>>>(ei, wsi+O_OFFR, wsi+O_LSTR, wsf+O_A1, Rh, wsf+O_Y, wsf+O_AGG0);
  k_h1B<<<NN/4,256,0,stream>>>(wsf+O_AGG0, w_out0, w_emb, w_sc0, w_up1, w_r0, wsi+O_SPEC, batch, wsf+O_H10, wsf+O_B, wsf+O_EACC);
  /* R buffer overwritten with R1 (R0 dead after k_agg0) */
  k_mlp<<<1024,256,0,stream>>>(wsf+O_FEAT, r1w1, r1w2, r1w3, wsf+W_W4C1, Rh);
  k_agg1<<<NN/4,256,0,stream>>>(ei, wsi+O_OFFR, wsi+O_LSTR, wsf+O_B, Rh, wsf+O_Y, wsf+O_AGG1);
  k_h2g2<<<NN/4,256,0,stream>>>(wsf+O_AGG1, wsf+O_H10, w_out1, w_sc1, w_m1, w_m2, w_r0,
                                wsf+W_OUT1T, wsf+W_SC1T, wsi+O_SPEC, batch,
                                wsf+O_DH10, wsf+O_EACC);
  /* dagg1 now lives in O_AGG1; dagg0 written over O_AGG0 */
  k_dB<<<NN/4,256,0,stream>>>(ei, wsi+O_OFFS, wsi+O_LSTS, wsf+O_AGG1, Rh, wsf+O_Y,
                              wsf+W_UP1T, wsf+W_OUT0T, wsf+O_DH10, wsf+O_AGG0);
  /* merged edge backward: both MLPs, one reduction set; 4 edges/wave */
  k_ebwd<<<NE/16,256,0,stream>>>(ei, wsf+O_A1, wsf+O_B,
                                 wsf+O_AGG0, wsf+O_AGG1, wsf+O_Y, wsf+O_FEAT, Rh,
                                 wsf+O_U, wsf+O_RB,
                                 r0w1, r0w2, r0w3, wsf+W_W2T0, wsf+W_W3T0, wsf+W_W4T0, r0w4,
                                 r1w1, r1w2, r1w3, wsf+W_W2T1, wsf+W_W3T1, wsf+W_W4T1,
                                 out+64);
  k_final<<<1,64,0,stream>>>(wsf+O_EACC, out);
}

// Round 13
// 2105.238 us; speedup vs baseline: 1.2642x; 1.2642x over previous
//
#include <hip/hip_runtime.h>
#include <cstddef>

#define NN 10000
#define NE 160000

#define S3  1.7320508075688772f
#define S5  2.2360679774997896f
#define S15 3.8729833462074170f
#define S25 0.6324555320336759f     /* sqrt(2/5) */
#define PI5 0.62831853071795864f    /* pi/5 */

/* CG path constants (analytic): CG(l,0,l)=I/sqrt(2l+1); CG(l,l,0)=(-1)^l I/sqrt(2l+1).
   Folded with the 1/AVG_NEIGH=1/16 segment-mean. */
#define C0_0 (1.f/16.f)
#define C0_1 (0.57735026918962576f/16.f)
#define C0_2 (0.44721359549995794f/16.f)
#define C1_0 (1.f/16.f)
#define C1_1 (-0.57735026918962576f/16.f)
#define C1_2 (0.44721359549995794f/16.f)

/* ---------------- workspace layout (4-byte element offsets), ~144 MB ------- */
constexpr size_t O_EACC = 0;                        // 64 f32 (zeroed)
constexpr size_t O_CNTR = 64;                       // NN int (zeroed)
constexpr size_t O_CNTS = O_CNTR + NN;
constexpr size_t O_CURR = O_CNTS + NN;
constexpr size_t O_CURS = O_CURR + NN;
constexpr size_t ZERO_ELEMS = O_CURS + NN;          // zeroed prefix
constexpr size_t O_SPEC = ZERO_ELEMS;               // NN int
constexpr size_t O_OFFR = O_SPEC + NN;              // NN+1 int
constexpr size_t O_OFFS = O_OFFR + NN + 8;          // NN+1 int
constexpr size_t O_LSTR = O_OFFS + NN + 8;          // NE int
constexpr size_t O_LSTS = O_LSTR + NE;              // NE int
constexpr size_t O_A1   = O_LSTS + NE;              // NN*64 f32
constexpr size_t O_U    = O_A1 + (size_t)NN*64;     // NE*3
constexpr size_t O_RB   = O_U + (size_t)NE*3;       // NE
constexpr size_t O_Y    = O_RB + NE;                // NE*8
constexpr size_t O_FEAT = O_Y + (size_t)NE*8;       // NE*8
constexpr size_t O_R    = O_FEAT + (size_t)NE*8;    // NE*192 bf16, R0 then R1
constexpr size_t O_AGG0 = O_R + (size_t)NE*96;      // NN*576  (agg0 then dagg0)
constexpr size_t O_H10  = O_AGG0 + (size_t)NN*576;  // NN*64
constexpr size_t O_B    = O_H10 + (size_t)NN*64;    // NN*576
constexpr size_t O_AGG1 = O_B + (size_t)NN*576;     // NN*192 (agg1 then dagg1)
constexpr size_t O_DH10 = O_AGG1 + (size_t)NN*192;  // NN*64
constexpr size_t O_OUT9 = O_DH10 + (size_t)NN*64;   // NE*8 (dr0, tgx, tgy, tgz)
constexpr size_t O_WT   = O_OUT9 + (size_t)NE*8;
constexpr size_t W_OUT0T = O_WT;                    // 3*4096
constexpr size_t W_UP1T  = W_OUT0T + 12288;         // 3*4096
constexpr size_t W_OUT1T = W_UP1T + 12288;          // 3*4096 (paths 0,4,9)
constexpr size_t W_SC1T  = W_OUT1T + 12288;         // 10*4096
constexpr size_t W_W2T0  = W_SC1T + 40960;          // 4096
constexpr size_t W_W3T0  = W_W2T0 + 4096;           // 4096
constexpr size_t W_W4T0  = W_W3T0 + 4096;           // 192*64   [o][k] = w4[k][o]
constexpr size_t W_W2T1  = W_W4T0 + 12288;          // 4096
constexpr size_t W_W3T1  = W_W2T1 + 4096;           // 4096
constexpr size_t W_W4T1  = W_W3T1 + 4096;           // 192*64   (cols 0,256,576 of r1w4)
constexpr size_t W_W4C1  = W_W4T1 + 12288;          // 64*192   [k][o] gathered cols of r1w4
constexpr size_t W_A1S   = W_W4C1 + 12288;          // 10*64
constexpr size_t TOTAL_ELEMS = W_A1S + 640;

__device__ __forceinline__ float rl(float v, int l){
  return __uint_as_float(__builtin_amdgcn_readlane(__float_as_uint(v), l));
}
__device__ __forceinline__ float wred(float v){
  #pragma unroll
  for(int m=32;m;m>>=1) v += __shfl_xor(v, m, 64);
  return v;
}
__device__ __forceinline__ float silu_f(float x){ float s=1.f/(1.f+expf(-x)); return x*s; }
__device__ __forceinline__ float dsilu_f(float x){ float s=1.f/(1.f+expf(-x)); return s*(1.f+x*(1.f-s)); }
__device__ __forceinline__ unsigned short f2b(float x){
  unsigned int u=__float_as_uint(x);
  unsigned int r=(u + 0x7fffu + ((u>>16)&1u))>>16;
  return (unsigned short)r;
}
__device__ __forceinline__ float b2f(unsigned short h){
  return __uint_as_float(((unsigned int)h)<<16);
}

/* -------------------- prep: transposed weights + per-species A1 ----------- */
__global__ __launch_bounds__(256) void k_prep(
    const float* __restrict__ w_out0, const float* __restrict__ w_up1,
    const float* __restrict__ w_out1, const float* __restrict__ w_sc1,
    const float* __restrict__ r0w2, const float* __restrict__ r0w3, const float* __restrict__ r0w4,
    const float* __restrict__ r1w2, const float* __restrict__ r1w3, const float* __restrict__ r1w4,
    const float* __restrict__ w_emb, const float* __restrict__ w_up0,
    float* __restrict__ ws)
{
  int t = blockIdx.x*256 + threadIdx.x;
  if (t < 12288){
    int l=t>>12, rem=t&4095, a=rem>>6, b=rem&63;
    ws[W_OUT0T+t] = w_out0[l*4096 + b*64 + a];
    ws[W_UP1T +t] = w_up1 [l*4096 + b*64 + a];
    int pl = (l==0)?0:((l==1)?4:9);
    ws[W_OUT1T+t] = w_out1[pl*4096 + b*64 + a];
  }
  if (t < 40960){
    int s=t>>12, rem=t&4095, a=rem>>6, b=rem&63;
    ws[W_SC1T+t] = w_sc1[(size_t)s*4096 + b*64 + a];
  }
  if (t < 4096){
    int a=t>>6, b=t&63;
    ws[W_W2T0+t]=r0w2[b*64+a];
    ws[W_W3T0+t]=r0w3[b*64+a];
    ws[W_W2T1+t]=r1w2[b*64+a];
    ws[W_W3T1+t]=r1w3[b*64+a];
  }
  if (t < 12288){
    int o=t>>6, k=t&63;
    ws[W_W4T0+t]=r0w4[k*192+o];
    int p=o>>6, c=o&63;
    int base=(p==0)?0:((p==1)?256:576);
    ws[W_W4T1+t]=r1w4[k*832+base+c];
  }
  if (t < 12288){
    int k=t/192, o=t%192;
    int p=o>>6, c=o&63;
    int base=(p==0)?0:((p==1)?256:576);
    ws[W_W4C1+t]=r1w4[k*832+base+c];
  }
  if (t < 640){
    int sp=t>>6, c=t&63;
    float acc=0.f;
    for(int k=0;k<64;k++) acc += w_emb[sp*64+k]*w_up0[k*64+c];
    ws[W_A1S+t]=acc;
  }
}

/* -------------------- species / embedding / e0 ---------------------------- */
__global__ __launch_bounds__(256) void k_spec(
    const float* __restrict__ attrs, const float* __restrict__ A1spec,
    const float* __restrict__ aen, const int* __restrict__ batch,
    int* __restrict__ spec, float* __restrict__ A1, float* __restrict__ eacc)
{
  int wv=(blockIdx.x*blockDim.x+threadIdx.x)>>6;
  if (wv>=NN) return;
  int lane=threadIdx.x&63;
  int sp=0;
  #pragma unroll
  for(int t=0;t<10;t++) if (attrs[(size_t)wv*10+t]>0.5f) sp=t;
  A1[(size_t)wv*64+lane]=A1spec[sp*64+lane];
  if(lane==0){
    spec[wv]=sp;
    atomicAdd(&eacc[batch[wv]*3+0], aen[sp]);
  }
}

/* ------ edge geometry: u, r, Y(l<=2), radial feats (sin recurrence) ------- */
__global__ __launch_bounds__(256) void k_geom(
    const float* __restrict__ pos, const float* __restrict__ shifts, const int* __restrict__ ei,
    float* __restrict__ ub, float* __restrict__ rb, float* __restrict__ Yb, float* __restrict__ fb,
    int* __restrict__ cntr, int* __restrict__ cnts)
{
  int e=blockIdx.x*256+threadIdx.x;
  if(e>=NE) return;
  int s=ei[e], rv=ei[NE+e];
  atomicAdd(&cnts[s],1);
  atomicAdd(&cntr[rv],1);
  float vx=pos[rv*3+0]-pos[s*3+0]+shifts[(size_t)e*3+0];
  float vy=pos[rv*3+1]-pos[s*3+1]+shifts[(size_t)e*3+1];
  float vz=pos[rv*3+2]-pos[s*3+2]+shifts[(size_t)e*3+2];
  float r=sqrtf(vx*vx+vy*vy+vz*vz+1e-12f);
  float inv=1.f/r;
  float x=vx*inv, y=vy*inv, z=vz*inv;
  ub[(size_t)e*3+0]=x; ub[(size_t)e*3+1]=y; ub[(size_t)e*3+2]=z;
  rb[e]=r;
  size_t yo=(size_t)e*8;
  Yb[yo+0]=S3*y;     Yb[yo+1]=S3*z;     Yb[yo+2]=S3*x;
  Yb[yo+3]=S15*x*y;  Yb[yo+4]=S15*y*z;  Yb[yo+5]=0.5f*S5*(3.f*z*z-1.f);
  Yb[yo+6]=S15*x*z;  Yb[yo+7]=0.5f*S15*(x*x-y*y);
  float u5=r*0.2f, fc=0.f;
  if(u5<1.f){
    float u2=u5*u5,u4=u2*u2,p5=u4*u5,p6=p5*u5,p7=p6*u5;
    fc=1.f-21.f*p5+35.f*p6-15.f*p7;
  }
  size_t fo=(size_t)e*8;
  /* sin(n*PI5*r) via angle-addition recurrence: 1 sincosf instead of 8 sinf */
  float s1v,c1v;
  sincosf(PI5*r,&s1v,&c1v);
  float base=S25*inv*fc;
  float sn=s1v, cn=c1v;
  fb[fo+0]=base*sn;
  #pragma unroll
  for(int n=2;n<=8;n++){
    float s2=sn*c1v+cn*s1v;
    float c2=cn*c1v-sn*s1v;
    sn=s2; cn=c2;
    fb[fo+n-1]=base*sn;
  }
}

/* -------------------- CSR: both scans in one launch (2 blocks) ------------- */
__global__ __launch_bounds__(1024) void k_scan2(
    const int* __restrict__ cntr, const int* __restrict__ cnts,
    int* __restrict__ offr, int* __restrict__ offs)
{
  const int* __restrict__ cnt = blockIdx.x ? cnts : cntr;
  int* __restrict__ off = blockIdx.x ? offs : offr;
  __shared__ int sh[1024];
  __shared__ int sbase;
  int tid=threadIdx.x;
  if(tid==0) sbase=0;
  __syncthreads();
  for(int start=0;start<NN;start+=1024){
    int i=start+tid;
    int v=(i<NN)?cnt[i]:0;
    sh[tid]=v;
    __syncthreads();
    for(int o=1;o<1024;o<<=1){
      int t=(tid>=o)?sh[tid-o]:0;
      __syncthreads();
      sh[tid]+=t;
      __syncthreads();
    }
    int excl=sbase+sh[tid]-v;
    int tot=sh[1023];
    __syncthreads();
    if(i<NN) off[i]=excl;
    if(tid==0) sbase+=tot;
    __syncthreads();
  }
  if(tid==0) off[NN]=sbase;
}

__global__ __launch_bounds__(256) void k_fill(const int* __restrict__ ei,
    const int* __restrict__ offr, const int* __restrict__ offs,
    int* __restrict__ curr, int* __restrict__ curs,
    int* __restrict__ lstr, int* __restrict__ lsts)
{
  int e=blockIdx.x*256+threadIdx.x;
  if(e>=NE) return;
  int s=ei[e], rv=ei[NE+e];
  int p=atomicAdd(&curr[rv],1); lstr[offr[rv]+p]=e;
  int q=atomicAdd(&curs[s],1);  lsts[offs[s]+q]=e;
}

/* -------------------- radial MLP forward (wave = 4 edges), bf16 out -------- */
__global__ __launch_bounds__(256) void k_mlp(
    const float* __restrict__ feat,
    const float* __restrict__ w1, const float* __restrict__ w2,
    const float* __restrict__ w3, const float* __restrict__ w4c,
    unsigned short* __restrict__ R)
{
  __shared__ float lw4[12288];
  for(int i=threadIdx.x;i<12288;i+=256) lw4[i]=w4c[i];
  __syncthreads();
  int lane=threadIdx.x&63;
  int wv=(blockIdx.x*blockDim.x+threadIdx.x)>>6;
  int nwv=(gridDim.x*blockDim.x)>>6;
  for(int pr=wv; pr<NE/4; pr+=nwv){
    size_t e0=(size_t)pr*4;
    float z[4], t[4];
    #pragma unroll
    for(int i=0;i<4;i++) z[i]=0.f;
    #pragma unroll
    for(int b=0;b<8;b++){
      float w=w1[b*64+lane];
      #pragma unroll
      for(int i=0;i<4;i++) z[i]+=feat[(e0+i)*8+b]*w;
    }
    #pragma unroll
    for(int i=0;i<4;i++){ t[i]=silu_f(z[i]); z[i]=0.f; }
    #pragma unroll 8
    for(int k=0;k<64;k++){
      float w=w2[k*64+lane];
      #pragma unroll
      for(int i=0;i<4;i++) z[i]+=rl(t[i],k)*w;
    }
    #pragma unroll
    for(int i=0;i<4;i++){ t[i]=silu_f(z[i]); z[i]=0.f; }
    #pragma unroll 8
    for(int k=0;k<64;k++){
      float w=w3[k*64+lane];
      #pragma unroll
      for(int i=0;i<4;i++) z[i]+=rl(t[i],k)*w;
    }
    #pragma unroll
    for(int i=0;i<4;i++) t[i]=silu_f(z[i]);
    float oA[4],oB[4],oC[4];
    #pragma unroll
    for(int i=0;i<4;i++){ oA[i]=0.f; oB[i]=0.f; oC[i]=0.f; }
    #pragma unroll 4
    for(int k=0;k<64;k++){
      float wA=lw4[k*192+lane], wB=lw4[k*192+64+lane], wC=lw4[k*192+128+lane];
      #pragma unroll
      for(int i=0;i<4;i++){
        float v=rl(t[i],k);
        oA[i]+=v*wA; oB[i]+=v*wB; oC[i]+=v*wC;
      }
    }
    #pragma unroll
    for(int i=0;i<4;i++){
      R[(e0+i)*192+lane]    =f2b(oA[i]);
      R[(e0+i)*192+64+lane] =f2b(oB[i]);
      R[(e0+i)*192+128+lane]=f2b(oC[i]);
    }
  }
}

/* -------------------- interaction 1 aggregation (gather by receiver) ------- */
__global__ __launch_bounds__(256) void k_agg0(
    const int* __restrict__ ei, const int* __restrict__ offr, const int* __restrict__ lstr,
    const float* __restrict__ A1, const unsigned short* __restrict__ R0, const float* __restrict__ Yb,
    float* __restrict__ agg0)
{
  int wv=(blockIdx.x*blockDim.x+threadIdx.x)>>6;
  if(wv>=NN) return;
  int lane=threadIdx.x&63;
  float a[9];
  #pragma unroll
  for(int q=0;q<9;q++) a[q]=0.f;
  int i0=offr[wv], i1=offr[wv+1];
  for(int i=i0;i<i1;i++){
    int e=lstr[i];
    int s=ei[e];
    float a1=A1[(size_t)s*64+lane];
    float t0=a1*b2f(R0[(size_t)e*192+lane]);
    float t1=a1*b2f(R0[(size_t)e*192+64+lane]);
    float t2=a1*b2f(R0[(size_t)e*192+128+lane]);
    a[0]+=t0;
    #pragma unroll
    for(int j=0;j<3;j++) a[1+j]+=Yb[(size_t)e*8+j]*t1;
    #pragma unroll
    for(int j=0;j<5;j++) a[4+j]+=Yb[(size_t)e*8+3+j]*t2;
  }
  size_t o=(size_t)wv*576;
  agg0[o+lane]=a[0]*C0_0;
  #pragma unroll
  for(int j=0;j<3;j++) agg0[o+(1+j)*64+lane]=a[1+j]*C0_1;
  #pragma unroll
  for(int j=0;j<5;j++) agg0[o+(4+j)*64+lane]=a[4+j]*C0_2;
}

/* -------------------- h1 (+sc, e1) and B = h1 @ w_up1 ---------------------- */
__global__ __launch_bounds__(256) void k_h1B(
    const float* __restrict__ agg0, const float* __restrict__ w_out0,
    const float* __restrict__ w_emb, const float* __restrict__ w_sc0,
    const float* __restrict__ w_up1, const float* __restrict__ w_r0,
    const int* __restrict__ spec, const int* __restrict__ batch,
    float* __restrict__ h1_0, float* __restrict__ Bv, float* __restrict__ eacc)
{
  int wv=(blockIdx.x*blockDim.x+threadIdx.x)>>6;
  if(wv>=NN) return;
  int lane=threadIdx.x&63;
  float aq[9], h[9];
  #pragma unroll
  for(int q=0;q<9;q++){ aq[q]=agg0[(size_t)wv*576+q*64+lane]; h[q]=0.f; }
  #pragma unroll 4
  for(int c=0;c<64;c++){
    float w0=w_out0[c*64+lane], wl1=w_out0[4096+c*64+lane], wl2=w_out0[8192+c*64+lane];
    h[0]+=rl(aq[0],c)*w0;
    h[1]+=rl(aq[1],c)*wl1; h[2]+=rl(aq[2],c)*wl1; h[3]+=rl(aq[3],c)*wl1;
    h[4]+=rl(aq[4],c)*wl2; h[5]+=rl(aq[5],c)*wl2; h[6]+=rl(aq[6],c)*wl2;
    h[7]+=rl(aq[7],c)*wl2; h[8]+=rl(aq[8],c)*wl2;
  }
  int sp=spec[wv];
  #pragma unroll 8
  for(int c=0;c<64;c++) h[0]+=w_emb[sp*64+c]*w_sc0[(size_t)sp*4096+c*64+lane];
  h1_0[(size_t)wv*64+lane]=h[0];
  float p=wred(h[0]*w_r0[lane]);
  if(lane==0) atomicAdd(&eacc[batch[wv]*3+1],p);
  float Bo[9];
  #pragma unroll
  for(int q=0;q<9;q++) Bo[q]=0.f;
  #pragma unroll 4
  for(int c=0;c<64;c++){
    float u0=w_up1[c*64+lane], u1=w_up1[4096+c*64+lane], u2=w_up1[8192+c*64+lane];
    Bo[0]+=rl(h[0],c)*u0;
    Bo[1]+=rl(h[1],c)*u1; Bo[2]+=rl(h[2],c)*u1; Bo[3]+=rl(h[3],c)*u1;
    Bo[4]+=rl(h[4],c)*u2; Bo[5]+=rl(h[5],c)*u2; Bo[6]+=rl(h[6],c)*u2;
    Bo[7]+=rl(h[7],c)*u2; Bo[8]+=rl(h[8],c)*u2;
  }
  #pragma unroll
  for(int q=0;q<9;q++) Bv[(size_t)wv*576+q*64+lane]=Bo[q];
}

/* -------------------- interaction 2 aggregation (l3=0 paths) --------------- */
__global__ __launch_bounds__(256) void k_agg1(
    const int* __restrict__ ei, const int* __restrict__ offr, const int* __restrict__ lstr,
    const float* __restrict__ Bv, const unsigned short* __restrict__ R1, const float* __restrict__ Yb,
    float* __restrict__ agg1)
{
  int wv=(blockIdx.x*blockDim.x+threadIdx.x)>>6;
  if(wv>=NN) return;
  int lane=threadIdx.x&63;
  float accA=0.f, accB=0.f, accC=0.f;
  int i0=offr[wv], i1=offr[wv+1];
  for(int i=i0;i<i1;i++){
    int e=lstr[i];
    int s=ei[e];
    size_t bo=(size_t)s*576;
    accA += b2f(R1[(size_t)e*192+lane])*Bv[bo+lane];
    float tb=0.f;
    #pragma unroll
    for(int j=0;j<3;j++) tb += Yb[(size_t)e*8+j]*Bv[bo+(1+j)*64+lane];
    accB += b2f(R1[(size_t)e*192+64+lane])*tb;
    float tc=0.f;
    #pragma unroll
    for(int j=0;j<5;j++) tc += Yb[(size_t)e*8+3+j]*Bv[bo+(4+j)*64+lane];
    accC += b2f(R1[(size_t)e*192+128+lane])*tc;
  }
  agg1[(size_t)wv*192+lane]     = accA*C1_0;
  agg1[(size_t)wv*192+64+lane]  = accB*C1_1;
  agg1[(size_t)wv*192+128+lane] = accC*C1_2;
}

/* ------- h2, e2, g2; dagg1 written IN PLACE over agg1 (same wave slots) ---- */
__global__ __launch_bounds__(256) void k_h2g2(
    float* __restrict__ agg1, const float* __restrict__ h1_0,
    const float* __restrict__ w_out1, const float* __restrict__ w_sc1,
    const float* __restrict__ w_m1, const float* __restrict__ w_m2,
    const float* __restrict__ w_r0,
    const float* __restrict__ w_out1T, const float* __restrict__ w_sc1T,
    const int* __restrict__ spec, const int* __restrict__ batch,
    float* __restrict__ dh10, float* __restrict__ eacc)
{
  int wv=(blockIdx.x*blockDim.x+threadIdx.x)>>6;
  if(wv>=NN) return;
  int lane=threadIdx.x&63;
  int sp=spec[wv];
  float a0=agg1[(size_t)wv*192+lane], a1=agg1[(size_t)wv*192+64+lane], a2=agg1[(size_t)wv*192+128+lane];
  float hh=h1_0[(size_t)wv*64+lane];
  float h2=0.f;
  #pragma unroll 4
  for(int c=0;c<64;c++){
    h2 += rl(a0,c)*w_out1[c*64+lane];
    h2 += rl(a1,c)*w_out1[4*4096+c*64+lane];
    h2 += rl(a2,c)*w_out1[9*4096+c*64+lane];
    h2 += rl(hh,c)*w_sc1[(size_t)sp*4096+c*64+lane];
  }
  int tt=lane&15;
  float z=0.f;
  #pragma unroll 8
  for(int d=0;d<64;d++) z+=rl(h2,d)*w_m1[d*16+tt];
  float sg=1.f/(1.f+expf(-z));
  float e2p=(lane<16)? w_m2[tt]*z*sg : 0.f;
  e2p=wred(e2p);
  if(lane==0) atomicAdd(&eacc[batch[wv]*3+2],e2p);
  float st=w_m2[tt]*sg*(1.f+z*(1.f-sg));
  float g=0.f;
  #pragma unroll
  for(int t=0;t<16;t++) g+=rl(st,t)*w_m1[lane*16+t];
  float d0=0.f,d1=0.f,d2=0.f,dh=0.f;
  #pragma unroll 4
  for(int d=0;d<64;d++){
    float gd=rl(g,d);
    d0+=gd*w_out1T[d*64+lane];
    d1+=gd*w_out1T[4096+d*64+lane];
    d2+=gd*w_out1T[8192+d*64+lane];
    dh+=gd*w_sc1T[(size_t)sp*4096+d*64+lane];
  }
  agg1[(size_t)wv*192+lane]=d0;
  agg1[(size_t)wv*192+64+lane]=d1;
  agg1[(size_t)wv*192+128+lane]=d2;
  dh10[(size_t)wv*64+lane]=dh+w_r0[lane];
}

/* --- dB (gather by sender) -> dh1 -> dagg0 (written over agg0 buffer) ------ */
__global__ __launch_bounds__(256) void k_dB(
    const int* __restrict__ ei, const int* __restrict__ offs, const int* __restrict__ lsts,
    const float* __restrict__ dagg1, const unsigned short* __restrict__ R1, const float* __restrict__ Yb,
    const float* __restrict__ w_up1T, const float* __restrict__ w_out0T,
    const float* __restrict__ dh10,
    float* __restrict__ dagg0)
{
  int wv=(blockIdx.x*blockDim.x+threadIdx.x)>>6;
  if(wv>=NN) return;
  int lane=threadIdx.x&63;
  float dB[9];
  #pragma unroll
  for(int q=0;q<9;q++) dB[q]=0.f;
  int i0=offs[wv], i1=offs[wv+1];
  for(int i=i0;i<i1;i++){
    int e=lsts[i];
    int rv=ei[NE+e];
    float t0=dagg1[(size_t)rv*192+lane]*C1_0*b2f(R1[(size_t)e*192+lane]);
    float t1=dagg1[(size_t)rv*192+64+lane]*C1_1*b2f(R1[(size_t)e*192+64+lane]);
    float t2=dagg1[(size_t)rv*192+128+lane]*C1_2*b2f(R1[(size_t)e*192+128+lane]);
    dB[0]+=t0;
    #pragma unroll
    for(int j=0;j<3;j++) dB[1+j]+=t1*Yb[(size_t)e*8+j];
    #pragma unroll
    for(int j=0;j<5;j++) dB[4+j]+=t2*Yb[(size_t)e*8+3+j];
  }
  float dh[9];
  #pragma unroll
  for(int q=0;q<9;q++) dh[q]=0.f;
  #pragma unroll 4
  for(int c=0;c<64;c++){
    float u0=w_up1T[c*64+lane], u1=w_up1T[4096+c*64+lane], u2=w_up1T[8192+c*64+lane];
    dh[0]+=rl(dB[0],c)*u0;
    dh[1]+=rl(dB[1],c)*u1; dh[2]+=rl(dB[2],c)*u1; dh[3]+=rl(dB[3],c)*u1;
    dh[4]+=rl(dB[4],c)*u2; dh[5]+=rl(dB[5],c)*u2; dh[6]+=rl(dB[6],c)*u2;
    dh[7]+=rl(dB[7],c)*u2; dh[8]+=rl(dB[8],c)*u2;
  }
  dh[0]+=dh10[(size_t)wv*64+lane];
  float dg[9];
  #pragma unroll
  for(int q=0;q<9;q++) dg[q]=0.f;
  #pragma unroll 4
  for(int d=0;d<64;d++){
    float o0=w_out0T[d*64+lane], o1=w_out0T[4096+d*64+lane], o2=w_out0T[8192+d*64+lane];
    dg[0]+=rl(dh[0],d)*o0;
    dg[1]+=rl(dh[1],d)*o1; dg[2]+=rl(dh[2],d)*o1; dg[3]+=rl(dh[3],d)*o1;
    dg[4]+=rl(dh[4],d)*o2; dg[5]+=rl(dh[5],d)*o2; dg[6]+=rl(dh[6],d)*o2;
    dg[7]+=rl(dh[7],d)*o2; dg[8]+=rl(dh[8],d)*o2;
  }
  #pragma unroll
  for(int q=0;q<9;q++) dagg0[(size_t)wv*576+q*64+lane]=dg[q];
}

/* ---- MLP forward (4 edges/wave, lane=channel); RC: also R cols 1,2 ------- */
template<bool RC>
__device__ __forceinline__ void mlp_fwd4(
    int lane, int eb0, const float* __restrict__ feat,
    const float* __restrict__ w1, const float* __restrict__ w2,
    const float* __restrict__ w3, const float* __restrict__ w4C,
    float z1[4], float z2[4], float z3[4], float rc0[4], float rc1[4])
{
  float t[4], acc[4];
  #pragma unroll
  for(int i=0;i<4;i++) z1[i]=0.f;
  #pragma unroll
  for(int b=0;b<8;b++){
    float w=w1[b*64+lane];
    #pragma unroll
    for(int i=0;i<4;i++) z1[i]+=feat[(size_t)(eb0+i)*8+b]*w;
  }
  #pragma unroll
  for(int i=0;i<4;i++){ t[i]=silu_f(z1[i]); acc[i]=0.f; }
  #pragma unroll 8
  for(int k=0;k<64;k++){
    float w=w2[k*64+lane];
    #pragma unroll
    for(int i=0;i<4;i++) acc[i]+=rl(t[i],k)*w;
  }
  #pragma unroll
  for(int i=0;i<4;i++){ z2[i]=acc[i]; t[i]=silu_f(acc[i]); acc[i]=0.f; }
  #pragma unroll 8
  for(int k=0;k<64;k++){
    float w=w3[k*64+lane];
    #pragma unroll
    for(int i=0;i<4;i++) acc[i]+=rl(t[i],k)*w;
  }
  #pragma unroll
  for(int i=0;i<4;i++) z3[i]=acc[i];
  if(RC){
    float a2[4];
    #pragma unroll
    for(int i=0;i<4;i++){ t[i]=silu_f(z3[i]); acc[i]=0.f; a2[i]=0.f; }
    #pragma unroll 8
    for(int k=0;k<64;k++){
      float wB=w4C[k*192+64+lane], wC=w4C[k*192+128+lane];
      #pragma unroll
      for(int i=0;i<4;i++){ float v=rl(t[i],k); acc[i]+=v*wB; a2[i]+=v*wC; }
    }
    #pragma unroll
    for(int i=0;i<4;i++){ rc0[i]=acc[i]; rc1[i]=a2[i]; }
  }
}

/* ---- MLP backward core (4 edges): dR -> dz1*q (per-lane) ------------------ */
__device__ __forceinline__ void mlp_bwd4(
    int lane,
    const float* __restrict__ w2T, const float* __restrict__ w3T,
    const float* __restrict__ w4T,
    const float z1[4], const float z2[4], const float z3[4],
    const float dRa[4], const float dRb[4], const float dRc[4],
    const float qv[4], float dracc[4])
{
  float t[4], acc[4];
  #pragma unroll
  for(int i=0;i<4;i++) acc[i]=0.f;
  #pragma unroll 8
  for(int k=0;k<64;k++){
    float w=w4T[k*64+lane];
    #pragma unroll
    for(int i=0;i<4;i++) acc[i]+=rl(dRa[i],k)*w;
  }
  #pragma unroll 8
  for(int k=0;k<64;k++){
    float w=w4T[4096+k*64+lane];
    #pragma unroll
    for(int i=0;i<4;i++) acc[i]+=rl(dRb[i],k)*w;
  }
  #pragma unroll 8
  for(int k=0;k<64;k++){
    float w=w4T[8192+k*64+lane];
    #pragma unroll
    for(int i=0;i<4;i++) acc[i]+=rl(dRc[i],k)*w;
  }
  #pragma unroll
  for(int i=0;i<4;i++){ t[i]=acc[i]*dsilu_f(z3[i]); acc[i]=0.f; }
  #pragma unroll 8
  for(int k=0;k<64;k++){
    float w=w3T[k*64+lane];
    #pragma unroll
    for(int i=0;i<4;i++) acc[i]+=rl(t[i],k)*w;
  }
  #pragma unroll
  for(int i=0;i<4;i++){ t[i]=acc[i]*dsilu_f(z2[i]); acc[i]=0.f; }
  #pragma unroll 8
  for(int k=0;k<64;k++){
    float w=w2T[k*64+lane];
    #pragma unroll
    for(int i=0;i<4;i++) acc[i]+=rl(t[i],k)*w;
  }
  #pragma unroll
  for(int i=0;i<4;i++) dracc[i]=acc[i]*dsilu_f(z1[i])*qv[i];
}

/* -- radial-derivative prelude: q[i][c] = sum_b w1[b][c]*d(rad_b)/dr -------- */
__device__ __forceinline__ void rad_q4(
    int lane, int eb0, const float* __restrict__ rb, const float* __restrict__ w1,
    float q[4])
{
  int i8=(lane>>3)&3, b8=lane&7;
  float re=rb[eb0+i8];
  float ivre=1.f/re;
  float u5=re*0.2f, fcut=0.f, dfcut=0.f;
  if(u5<1.f){
    float u2=u5*u5,u4=u2*u2,p5=u4*u5,p6=p5*u5,p7=p6*u5;
    fcut=1.f-21.f*p5+35.f*p6-15.f*p7;
    dfcut=(-105.f*u4+210.f*p5-105.f*p6)*0.2f;
  }
  float kn=(b8+1)*PI5;
  float sn,cn; sincosf(kn*re,&sn,&cn);
  float radv=(S25*(kn*cn-sn*ivre)*ivre)*fcut + (S25*sn*ivre)*dfcut;
  #pragma unroll
  for(int i=0;i<4;i++) q[i]=0.f;
  #pragma unroll
  for(int b=0;b<8;b++){
    float w=w1[b*64+lane];
    #pragma unroll
    for(int i=0;i<4;i++) q[i]+=rl(radv,i*8+b)*w;
  }
}

/* ------ edge backward, MLP0 side: out4[e] = {dr0, tgx, tgy, tgz} -----------
   dY[8] folded linearly into per-lane (gx,gy,gz) partials -> 3 wreds/edge. */
__global__ __launch_bounds__(256) void k_ebwd0(
    const int* __restrict__ ei,
    const float* __restrict__ A1, const float* __restrict__ dagg0,
    const float* __restrict__ Yb, const float* __restrict__ feat,
    const float* __restrict__ ub, const float* __restrict__ rb,
    const float* __restrict__ w1, const float* __restrict__ w2, const float* __restrict__ w3,
    const float* __restrict__ w2T, const float* __restrict__ w3T, const float* __restrict__ w4T,
    const float* __restrict__ w4C,
    float* __restrict__ out4)
{
  int wv=(blockIdx.x*blockDim.x+threadIdx.x)>>6;
  int lane=threadIdx.x&63;
  int eb0=wv*4;
  if(eb0>=NE) return;

  float q[4];
  rad_q4(lane, eb0, rb, w1, q);

  float z1[4],z2[4],z3[4],rc0[4],rc1[4];
  mlp_fwd4<true>(lane, eb0, feat, w1, w2, w3, w4C, z1,z2,z3, rc0,rc1);

  /* single dagg0 gather: feeds dR0 AND per-lane (tgx,tgy,tgz) partials */
  float dRa[4],dRb[4],dRc[4];
  #pragma unroll
  for(int i=0;i<4;i++){
    int e=eb0+i;
    int s=ei[e], rv=ei[NE+e];
    float A1a=A1[(size_t)s*64+lane];
    const float* dg=&dagg0[(size_t)rv*576];
    const float* Yv=&Yb[(size_t)e*8];
    float P0=C0_1*A1a*rc0[i], P1=C0_2*A1a*rc1[i];
    dRa[i]=C0_0*A1a*dg[lane];
    float ux=ub[(size_t)e*3], uy=ub[(size_t)e*3+1], uz=ub[(size_t)e*3+2];
    float d0=dg[64+lane],  d1=dg[128+lane], d2=dg[192+lane];
    float d3=dg[256+lane], d4=dg[320+lane], d5=dg[384+lane];
    float d6=dg[448+lane], d7=dg[512+lane];
    float s1=Yv[0]*d0+Yv[1]*d1+Yv[2]*d2;
    float s2=Yv[3]*d3+Yv[4]*d4+Yv[5]*d5+Yv[6]*d6+Yv[7]*d7;
    float y0=P0*d0, y1=P0*d1, y2=P0*d2;
    float y3=P1*d3, y4=P1*d4, y5=P1*d5, y6=P1*d6, y7=P1*d7;
    float gxl=S3*y2+S15*(y3*uy+y6*uz)+S15*y7*ux;
    float gyl=S3*y0+S15*(y3*ux+y4*uz)-S15*y7*uy;
    float gzl=S3*y1+S15*(y4*uy+y6*ux)+3.f*S5*y5*uz;
    gxl=wred(gxl); gyl=wred(gyl); gzl=wred(gzl);
    dRb[i]=C0_1*A1a*s1;
    dRc[i]=C0_2*A1a*s2;
    if(lane==0){
      out4[(size_t)e*8+1]=gxl;
      out4[(size_t)e*8+2]=gyl;
      out4[(size_t)e*8+3]=gzl;
    }
  }

  float dracc[4];
  mlp_bwd4(lane, w2T, w3T, w4T, z1,z2,z3, dRa,dRb,dRc, q, dracc);
  #pragma unroll
  for(int i=0;i<4;i++){
    float d0=wred(dracc[i]);
    if(lane==0) out4[(size_t)(eb0+i)*8]=d0;
  }
}

/* ------ edge backward, MLP1 side + force assembly -------------------------- */
__global__ __launch_bounds__(256) void k_ebwd1(
    const int* __restrict__ ei,
    const float* __restrict__ Bv, const float* __restrict__ dagg1,
    const float* __restrict__ Yb, const float* __restrict__ feat,
    const unsigned short* __restrict__ Rh,
    const float* __restrict__ ub, const float* __restrict__ rb,
    const float* __restrict__ w1, const float* __restrict__ w2, const float* __restrict__ w3,
    const float* __restrict__ w2T, const float* __restrict__ w3T, const float* __restrict__ w4T,
    const float* __restrict__ out4,
    float* __restrict__ F)
{
  int wv=(blockIdx.x*blockDim.x+threadIdx.x)>>6;
  int lane=threadIdx.x&63;
  int eb0=wv*4;
  if(eb0>=NE) return;

  float q[4];
  rad_q4(lane, eb0, rb, w1, q);

  float z1[4],z2[4],z3[4],rcd0[4],rcd1[4];
  mlp_fwd4<false>(lane, eb0, feat, w1, w2, w3, nullptr, z1,z2,z3, rcd0,rcd1);

  /* single Bv/dagg1 gather: feeds dR1 AND the tangential force directly */
  float dRa[4],dRb[4],dRc[4];
  float fx[4],fy[4],fz[4];
  #pragma unroll
  for(int i=0;i<4;i++){
    int e=eb0+i;
    int s=ei[e], rv=ei[NE+e];
    const float* Bq=&Bv[(size_t)s*576];
    const float* dq=&dagg1[(size_t)rv*192];
    const float* Yv=&Yb[(size_t)e*8];
    const float* o4=&out4[(size_t)e*8];
    float dq0=dq[lane], dq1=dq[64+lane], dq2=dq[128+lane];
    float r1c0=b2f(Rh[(size_t)e*192+64+lane]);
    float r1c1=b2f(Rh[(size_t)e*192+128+lane]);
    float P1=C1_1*r1c0*dq1, P2=C1_2*r1c1*dq2;
    dRa[i]=C1_0*dq0*Bq[lane];
    float b0=Bq[64+lane],  b1=Bq[128+lane], b2=Bq[192+lane];
    float b3=Bq[256+lane], b4=Bq[320+lane], b5=Bq[384+lane];
    float b6=Bq[448+lane], b7=Bq[512+lane];
    float s1=Yv[0]*b0+Yv[1]*b1+Yv[2]*b2;
    float s2=Yv[3]*b3+Yv[4]*b4+Yv[5]*b5+Yv[6]*b6+Yv[7]*b7;
    float y0=P1*b0, y1=P1*b1, y2=P1*b2;
    float y3=P2*b3, y4=P2*b4, y5=P2*b5, y6=P2*b6, y7=P2*b7;
    float ux=ub[(size_t)e*3], uyy=ub[(size_t)e*3+1], uz=ub[(size_t)e*3+2];
    float gxl=S3*y2+S15*(y3*uyy+y6*uz)+S15*y7*ux;
    float gyl=S3*y0+S15*(y3*ux+y4*uz)-S15*y7*uyy;
    float gzl=S3*y1+S15*(y4*uyy+y6*ux)+3.f*S5*y5*uz;
    float gx=o4[1]+wred(gxl);
    float gy=o4[2]+wred(gyl);
    float gz=o4[3]+wred(gzl);
    dRb[i]=C1_1*dq1*s1;
    dRc[i]=C1_2*dq2*s2;
    float ivr=1.f/rb[e];
    float dot=gx*ux+gy*uyy+gz*uz;
    fx[i]=(gx-dot*ux)*ivr;
    fy[i]=(gy-dot*uyy)*ivr;
    fz[i]=(gz-dot*uz)*ivr;
  }

  float dracc[4];
  mlp_bwd4(lane, w2T, w3T, w4T, z1,z2,z3, dRa,dRb,dRc, q, dracc);

  #pragma unroll
  for(int i=0;i<4;i++){
    int e=eb0+i;
    int s=ei[e], rv=ei[NE+e];
    float dr=out4[(size_t)e*8]+wred(dracc[i]);
    float ux=ub[(size_t)e*3], uyy=ub[(size_t)e*3+1], uz=ub[(size_t)e*3+2];
    float dvx=fx[i]+dr*ux;
    float dvy=fy[i]+dr*uyy;
    float dvz=fz[i]+dr*uz;
    if(lane==0){
      atomicAdd(&F[rv*3+0],-dvx); atomicAdd(&F[rv*3+1],-dvy); atomicAdd(&F[rv*3+2],-dvz);
      atomicAdd(&F[s*3+0],  dvx); atomicAdd(&F[s*3+1],  dvy); atomicAdd(&F[s*3+2],  dvz);
    }
  }
}

/* -------------------- finalize energies ------------------------------------ */
__global__ __launch_bounds__(64) void k_final(const float* __restrict__ eacc, float* __restrict__ out)
{
  int g=threadIdx.x;
  if(g<16){
    float a=eacc[g*3], b=eacc[g*3+1], c=eacc[g*3+2];
    out[g]=a+b+c;
    out[16+g*3+0]=a; out[16+g*3+1]=b; out[16+g*3+2]=c;
  }
}

extern "C" void kernel_launch(void* const* d_in, const int* in_sizes, int n_in,
                              void* d_out, int out_size, void* d_ws, size_t ws_size,
                              hipStream_t stream)
{
  (void)in_sizes; (void)n_in;
  if (ws_size < TOTAL_ELEMS*sizeof(float)) return;

  const float* pos   =(const float*)d_in[0];
  const float* attrs =(const float*)d_in[1];
  const float* shifts=(const float*)d_in[2];
  const float* aen   =(const float*)d_in[3];
  const float* w_emb =(const float*)d_in[4];
  const float* w_up0 =(const float*)d_in[5];
  const float* r0w1  =(const float*)d_in[6];
  const float* r0w2  =(const float*)d_in[7];
  const float* r0w3  =(const float*)d_in[8];
  const float* r0w4  =(const float*)d_in[9];
  const float* w_out0=(const float*)d_in[10];
  const float* w_sc0 =(const float*)d_in[11];
  const float* w_r0  =(const float*)d_in[12];
  const float* w_up1 =(const float*)d_in[13];
  const float* r1w1  =(const float*)d_in[14];
  const float* r1w2  =(const float*)d_in[15];
  const float* r1w3  =(const float*)d_in[16];
  const float* r1w4  =(const float*)d_in[17];
  const float* w_out1=(const float*)d_in[18];
  const float* w_sc1 =(const float*)d_in[19];
  const float* w_m1  =(const float*)d_in[20];
  const float* w_m2  =(const float*)d_in[21];
  const int*   ei    =(const int*)d_in[22];
  const int*   batch =(const int*)d_in[23];

  float* wsf=(float*)d_ws;
  int*   wsi=(int*)d_ws;
  unsigned short* Rh=(unsigned short*)(wsf+O_R);
  float* out=(float*)d_out;

  hipMemsetAsync(d_ws, 0, ZERO_ELEMS*sizeof(float), stream);
  hipMemsetAsync(d_out, 0, (size_t)out_size*sizeof(float), stream);

  k_prep<<<160,256,0,stream>>>(w_out0,w_up1,w_out1,w_sc1,r0w2,r0w3,r0w4,r1w2,r1w3,r1w4,w_emb,w_up0,wsf);
  k_spec<<<NN/4,256,0,stream>>>(attrs, wsf+W_A1S, aen, batch, wsi+O_SPEC, wsf+O_A1, wsf+O_EACC);
  k_geom<<<(NE+255)/256,256,0,stream>>>(pos, shifts, ei, wsf+O_U, wsf+O_RB, wsf+O_Y, wsf+O_FEAT,
                                        wsi+O_CNTR, wsi+O_CNTS);
  k_scan2<<<2,1024,0,stream>>>(wsi+O_CNTR, wsi+O_CNTS, wsi+O_OFFR, wsi+O_OFFS);
  k_fill<<<(NE+255)/256,256,0,stream>>>(ei, wsi+O_OFFR, wsi+O_OFFS, wsi+O_CURR, wsi+O_CURS, wsi+O_LSTR, wsi+O_LSTS);
  /* R buffer holds R0 here */
  k_mlp<<<1024,256,0,stream>>>(wsf+O_FEAT, r0w1, r0w2, r0w3, r0w4, Rh);
  k_agg0<<<NN/4,256,0,stream>>>(ei, wsi+O_OFFR, wsi+O_LSTR, wsf+O_A1, Rh, wsf+O_Y, wsf+O_AGG0);
  k_h1B<<<NN/4,256,0,stream>>>(wsf+O_AGG0, w_out0, w_emb, w_sc0, w_up1, w_r0, wsi+O_SPEC, batch, wsf+O_H10, wsf+O_B, wsf+O_EACC);
  /* R buffer overwritten with R1 (R0 dead after k_agg0) */
  k_mlp<<<1024,256,0,stream>>>(wsf+O_FEAT, r1w1, r1w2, r1w3, wsf+W_W4C1, Rh);
  k_agg1<<<NN/4,256,0,stream>>>(ei, wsi+O_OFFR, wsi+O_LSTR, wsf+O_B, Rh, wsf+O_Y, wsf+O_AGG1);
  k_h2g2<<<NN/4,256,0,stream>>>(wsf+O_AGG1, wsf+O_H10, w_out1, w_sc1, w_m1, w_m2, w_r0,
                                wsf+W_OUT1T, wsf+W_SC1T, wsi+O_SPEC, batch,
                                wsf+O_DH10, wsf+O_EACC);
  /* dagg1 now lives in O_AGG1; dagg0 written over O_AGG0 */
  k_dB<<<NN/4,256,0,stream>>>(ei, wsi+O_OFFS, wsi+O_LSTS, wsf+O_AGG1, Rh, wsf+O_Y,
                              wsf+W_UP1T, wsf+W_OUT0T, wsf+O_DH10, wsf+O_AGG0);
  /* edge backward split: MLP0 side then MLP1+forces; 4 edges/wave */
  k_ebwd0<<<NE/16,256,0,stream>>>(ei, wsf+O_A1, wsf+O_AGG0, wsf+O_Y, wsf+O_FEAT,
                                  wsf+O_U, wsf+O_RB,
                                  r0w1, r0w2, r0w3, wsf+W_W2T0, wsf+W_W3T0, wsf+W_W4T0, r0w4,
                                  wsf+O_OUT9);
  k_ebwd1<<<NE/16,256,0,stream>>>(ei, wsf+O_B, wsf+O_AGG1, wsf+O_Y, wsf+O_FEAT, Rh,
                                  wsf+O_U, wsf+O_RB,
                                  r1w1, r1w2, r1w3, wsf+W_W2T1, wsf+W_W3T1, wsf+W_W4T1,
                                  wsf+O_OUT9, out+64);
  k_final<<<1,64,0,stream>>>(wsf+O_EACC, out);
}